// Round 7
// baseline (238.495 us; speedup 1.0000x reference)
//
#include <hip/hip_runtime.h>
#include <hip/hip_bf16.h>

// N_NODES=100000, N_EDGES=800000, FEAT=64, NNZ=1600000
// Inputs: 0 edge_list [N,64] f32 | 1 X1 [E,2] i32 | 2 W [64,64] f32 | 3 b [64] f32
//         4 prelu_w [1] f32 | 5 b1_rows [NNZ] i32 | 6 b1_cols [NNZ] i32 | 7 b1_vals [NNZ] f32
// Output: [N,64] f32
//
// out = PReLU( (B1 @ Xe) @ W^T + (B1 @ 1) b^T ),  Xe[c] = (n[u_c]-n[v_c])^2
//
// Round-7: two-phase fill (depth-2 chains, no atomic->store dependency):
//   A: slot[i] = atomicAdd(cnt[rows[i]]) fused with f32->bf16 node convert
//      (independent block sections in ONE dispatch; convert hides under
//      atomic latency).
//   B: entries[r*CAP+slot] = {u,w,val} -- coalesced loads + 1 gather + 1
//      fire-and-forget scatter store. No atomics.
// gather (bf16 table, x4 unroll) and MFMA gemm unchanged from round 6.
// slot[] overlays aggb (disjoint lifetimes) -> ws need unchanged (128.8 MB).

#define FEAT 64
#define CAP  64   // Poisson(16) row degree; P(deg>64) ~ 1e-15 per row, guarded

typedef __attribute__((ext_vector_type(8))) short bf16x8;
typedef __attribute__((ext_vector_type(8))) unsigned short u16x8;
typedef __attribute__((ext_vector_type(4))) float f32x4;

__device__ inline short f2bf(float x) {
  union { __hip_bfloat16 h; short s; } u;
  u.h = __float2bfloat16(x);   // RNE
  return u.s;
}
__device__ inline float bf2f(unsigned short s) {
  return __uint_as_float((unsigned)s << 16);
}

// ---------------------------------------------------------------------------
// Kernel A: fused {f32->bf16 node convert} + {slot assignment histogram}.
// Blocks [0, CONV_BLOCKS) convert; the rest do slot[i]=atomicAdd(cnt[r],1).
// ---------------------------------------------------------------------------
#define CONV_BLOCKS 1024

__global__ __launch_bounds__(256) void convert_and_slot_kernel(
    const float* __restrict__ nodes,      // [N*64]
    unsigned short* __restrict__ nb,      // [N*64] bf16 out
    int n8,                               // (N*64)/8
    const int*   __restrict__ rows,       // [NNZ]
    int*         __restrict__ cnt,        // [N] pre-zeroed
    int*         __restrict__ slot,       // [NNZ] out
    int nnz) {
  const int b = blockIdx.x;
  if (b < CONV_BLOCKS) {
    for (int i = b * 256 + threadIdx.x; i < n8; i += CONV_BLOCKS * 256) {
      const f32x4 a = *reinterpret_cast<const f32x4*>(&nodes[i * 8]);
      const f32x4 c = *reinterpret_cast<const f32x4*>(&nodes[i * 8 + 4]);
      u16x8 o;
#pragma unroll
      for (int e = 0; e < 4; ++e) {
        o[e]     = (unsigned short)f2bf(a[e]);
        o[4 + e] = (unsigned short)f2bf(c[e]);
      }
      *reinterpret_cast<u16x8*>(&nb[i * 8]) = o;
    }
  } else {
    const int nblk = gridDim.x - CONV_BLOCKS;
    for (int i = (b - CONV_BLOCKS) * 256 + threadIdx.x; i < nnz;
         i += nblk * 256) {
      slot[i] = atomicAdd(&cnt[rows[i]], 1);
    }
  }
}

// ---------------------------------------------------------------------------
// Kernel B: scatter entries using precomputed slots. No atomics; the scatter
// store is fire-and-forget.
// ---------------------------------------------------------------------------
__global__ __launch_bounds__(256) void scatter_entries_kernel(
    const int*   __restrict__ rows,     // [NNZ]
    const int*   __restrict__ cols,     // [NNZ]
    const float* __restrict__ vals,     // [NNZ]
    const int*   __restrict__ X1,       // [E,2]
    const int*   __restrict__ slot,     // [NNZ]
    int4*        __restrict__ entries,  // [N*CAP]
    int nnz) {
  const int i = blockIdx.x * blockDim.x + threadIdx.x;
  if (i >= nnz) return;
  const int k = slot[i];
  if (k >= CAP) return;
  const int r = rows[i];
  const int2 uv = reinterpret_cast<const int2*>(X1)[cols[i]];
  const float v = vals[i];
  entries[(size_t)r * CAP + k] = make_int4(uv.x, uv.y, __float_as_int(v), 0);
}

// ---------------------------------------------------------------------------
// Kernel 2: per-row gather-aggregate from the bf16 node table, 4x unrolled.
// One wave per row; lane j = feature j. agg stored as bf16.
// ---------------------------------------------------------------------------
__global__ __launch_bounds__(256) void gather_agg_kernel(
    const unsigned short* __restrict__ nb,   // [N,64] bf16
    const int*   __restrict__ cnt,           // [N]
    const int4*  __restrict__ entries,       // [N*CAP]
    unsigned short* __restrict__ aggb,       // [N,64] bf16
    float*       __restrict__ rowsum,        // [N]
    int N) {
  const int lane = threadIdx.x & 63;
  const int r = blockIdx.x * (blockDim.x >> 6) + (threadIdx.x >> 6);
  if (r >= N) return;

  int deg = cnt[r];
  if (deg > CAP) deg = CAP;
  const int4* base = &entries[(size_t)r * CAP];

  float acc = 0.f, rsum = 0.f;

  for (int k = 0; k < deg; k += 4) {
    const int4 e0 = base[k + 0];
    const int4 e1 = base[k + 1];
    const int4 e2 = base[k + 2];
    const int4 e3 = base[k + 3];

    const bool m1 = (k + 1 < deg), m2 = (k + 2 < deg), m3 = (k + 3 < deg);
    const int   u0 = e0.x,            w0 = e0.y;
    const int   u1 = m1 ? e1.x : 0,   w1 = m1 ? e1.y : 0;
    const int   u2 = m2 ? e2.x : 0,   w2 = m2 ? e2.y : 0;
    const int   u3 = m3 ? e3.x : 0,   w3 = m3 ? e3.y : 0;
    const float v0 = __int_as_float(e0.z);
    const float v1 = m1 ? __int_as_float(e1.z) : 0.f;
    const float v2 = m2 ? __int_as_float(e2.z) : 0.f;
    const float v3 = m3 ? __int_as_float(e3.z) : 0.f;

    // 8 independent node-row gathers (128B coalesced each, bf16).
    const unsigned short a0 = nb[(size_t)u0 * FEAT + lane];
    const unsigned short b0 = nb[(size_t)w0 * FEAT + lane];
    const unsigned short a1 = nb[(size_t)u1 * FEAT + lane];
    const unsigned short b1 = nb[(size_t)w1 * FEAT + lane];
    const unsigned short a2 = nb[(size_t)u2 * FEAT + lane];
    const unsigned short b2 = nb[(size_t)w2 * FEAT + lane];
    const unsigned short a3 = nb[(size_t)u3 * FEAT + lane];
    const unsigned short b3 = nb[(size_t)w3 * FEAT + lane];

    rsum += (v0 + v1) + (v2 + v3);
    const float d0 = bf2f(a0) - bf2f(b0);
    const float d1 = bf2f(a1) - bf2f(b1);
    const float d2 = bf2f(a2) - bf2f(b2);
    const float d3 = bf2f(a3) - bf2f(b3);
    acc = fmaf(v0 * d0, d0, acc);
    acc = fmaf(v1 * d1, d1, acc);
    acc = fmaf(v2 * d2, d2, acc);
    acc = fmaf(v3 * d3, d3, acc);
  }

  aggb[(size_t)r * FEAT + lane] = (unsigned short)f2bf(acc);
  if (lane == 0) rowsum[r] = rsum;
}

// ---------------------------------------------------------------------------
// Kernel 3: out = PReLU( agg @ W^T + rowsum * b )  via mfma_f32_16x16x32_bf16.
// Fragment layouts (gfx950, m89/m91-verified):
//   A[i][k]: i = lane&15, k = (lane>>4)*8 + e   (e = 0..7)
//   B[k][j]: j = lane&15, k = (lane>>4)*8 + e
//   D[i][j]: j = lane&15, i = (lane>>4)*4 + reg (reg = 0..3)
// ---------------------------------------------------------------------------
__global__ __launch_bounds__(256) void final_gemm_kernel(
    const unsigned short* __restrict__ aggb,  // [N,64] bf16
    const float* __restrict__ rowsum,         // [N]
    const float* __restrict__ W,              // [64,64]
    const float* __restrict__ bias,           // [64]
    const float* __restrict__ pw,             // [1]
    float*       __restrict__ out,            // [N,64]
    int nrows) {
  const int lane = threadIdx.x & 63;
  const int gw = blockIdx.x * (blockDim.x >> 6) + (threadIdx.x >> 6);
  const int nw = gridDim.x * (blockDim.x >> 6);

  const int lrow = lane & 15;
  const int kgrp = lane >> 4;
  const int k0   = kgrp * 8;

  bf16x8 bfrag[4][2];
#pragma unroll
  for (int jt = 0; jt < 4; ++jt) {
#pragma unroll
    for (int ks = 0; ks < 2; ++ks) {
      const float* wr = &W[(jt * 16 + lrow) * FEAT + ks * 32 + k0];
      bf16x8 t;
#pragma unroll
      for (int e = 0; e < 8; ++e) t[e] = f2bf(wr[e]);
      bfrag[jt][ks] = t;
    }
  }
  const float slope = pw[0];
  float bj[4];
#pragma unroll
  for (int jt = 0; jt < 4; ++jt) bj[jt] = bias[jt * 16 + lrow];

  const int ntiles = nrows >> 4;   // 100000 / 16 = 6250
  for (int t = gw; t < ntiles; t += nw) {
    const int rowbase = t * 16;

    bf16x8 afrag[2];
#pragma unroll
    for (int ks = 0; ks < 2; ++ks) {
      afrag[ks] = *reinterpret_cast<const bf16x8*>(
          &aggb[(size_t)(rowbase + lrow) * FEAT + ks * 32 + k0]);
    }

    float rs[4];
#pragma unroll
    for (int reg = 0; reg < 4; ++reg) rs[reg] = rowsum[rowbase + kgrp * 4 + reg];

#pragma unroll
    for (int jt = 0; jt < 4; ++jt) {
      f32x4 acc = {0.f, 0.f, 0.f, 0.f};
      acc = __builtin_amdgcn_mfma_f32_16x16x32_bf16(afrag[0], bfrag[jt][0], acc, 0, 0, 0);
      acc = __builtin_amdgcn_mfma_f32_16x16x32_bf16(afrag[1], bfrag[jt][1], acc, 0, 0, 0);
#pragma unroll
      for (int reg = 0; reg < 4; ++reg) {
        float y = acc[reg] + rs[reg] * bj[jt];
        y = y >= 0.f ? y : slope * y;
        out[(size_t)(rowbase + kgrp * 4 + reg) * FEAT + jt * 16 + lrow] = y;
      }
    }
  }
}

// ---------------------------------------------------------------------------
// Fallback (ws too small): atomic scatter path + f32 GEMM (round-2).
// ---------------------------------------------------------------------------
__global__ __launch_bounds__(256) void scatter_xe_kernel(
    const float* __restrict__ nodes,
    const int*   __restrict__ X1,
    const int*   __restrict__ rows,
    const int*   __restrict__ cols,
    const float* __restrict__ vals,
    float*       __restrict__ agg,
    float*       __restrict__ rowsum,
    int nnz) {
  const int lane = threadIdx.x & 63;
  const int gw = blockIdx.x * (blockDim.x >> 6) + (threadIdx.x >> 6);
  const int nw = gridDim.x * (blockDim.x >> 6);
  for (int i = gw; i < nnz; i += nw) {
    const int r = rows[i];
    const int c = cols[i];
    const float v = vals[i];
    const int u = X1[2 * c + 0];
    const int w = X1[2 * c + 1];
    const float a = nodes[(size_t)u * FEAT + lane];
    const float b = nodes[(size_t)w * FEAT + lane];
    const float d = a - b;
    atomicAdd(&agg[(size_t)r * FEAT + lane], v * d * d);
    if (lane == 0) atomicAdd(&rowsum[r], v);
  }
}

__global__ __launch_bounds__(256) void final_gemm_f32_kernel(
    const float* __restrict__ agg, const float* __restrict__ rowsum,
    const float* __restrict__ W, const float* __restrict__ bias,
    const float* __restrict__ pw, float* __restrict__ out, int nrows) {
  const int lane = threadIdx.x & 63;
  const int gw = blockIdx.x * (blockDim.x >> 6) + (threadIdx.x >> 6);
  const int nw = gridDim.x * (blockDim.x >> 6);
  const int lrow = lane & 15;
  const int kgrp = lane >> 4;
  const int k0   = kgrp * 8;

  bf16x8 bfrag[4][2];
#pragma unroll
  for (int jt = 0; jt < 4; ++jt)
#pragma unroll
    for (int ks = 0; ks < 2; ++ks) {
      const float* wr = &W[(jt * 16 + lrow) * FEAT + ks * 32 + k0];
      bf16x8 t;
#pragma unroll
      for (int e = 0; e < 8; ++e) t[e] = f2bf(wr[e]);
      bfrag[jt][ks] = t;
    }
  const float slope = pw[0];
  float bj[4];
#pragma unroll
  for (int jt = 0; jt < 4; ++jt) bj[jt] = bias[jt * 16 + lrow];

  const int ntiles = nrows >> 4;
  for (int t = gw; t < ntiles; t += nw) {
    const int rowbase = t * 16;
    bf16x8 afrag[2];
#pragma unroll
    for (int ks = 0; ks < 2; ++ks) {
      const float* ar = &agg[(size_t)(rowbase + lrow) * FEAT + ks * 32 + k0];
      f32x4 a0 = *reinterpret_cast<const f32x4*>(ar);
      f32x4 a1 = *reinterpret_cast<const f32x4*>(ar + 4);
      bf16x8 ta;
#pragma unroll
      for (int e = 0; e < 4; ++e) { ta[e] = f2bf(a0[e]); ta[4 + e] = f2bf(a1[e]); }
      afrag[ks] = ta;
    }
    float rs[4];
#pragma unroll
    for (int reg = 0; reg < 4; ++reg) rs[reg] = rowsum[rowbase + kgrp * 4 + reg];
#pragma unroll
    for (int jt = 0; jt < 4; ++jt) {
      f32x4 acc = {0.f, 0.f, 0.f, 0.f};
      acc = __builtin_amdgcn_mfma_f32_16x16x32_bf16(afrag[0], bfrag[jt][0], acc, 0, 0, 0);
      acc = __builtin_amdgcn_mfma_f32_16x16x32_bf16(afrag[1], bfrag[jt][1], acc, 0, 0, 0);
#pragma unroll
      for (int reg = 0; reg < 4; ++reg) {
        float y = acc[reg] + rs[reg] * bj[jt];
        y = y >= 0.f ? y : slope * y;
        out[(size_t)(rowbase + kgrp * 4 + reg) * FEAT + jt * 16 + lrow] = y;
      }
    }
  }
}

extern "C" void kernel_launch(void* const* d_in, const int* in_sizes, int n_in,
                              void* d_out, int out_size, void* d_ws, size_t ws_size,
                              hipStream_t stream) {
  const float* nodes  = (const float*)d_in[0];
  const int*   X1     = (const int*)d_in[1];
  const float* W      = (const float*)d_in[2];
  const float* bias   = (const float*)d_in[3];
  const float* preluw = (const float*)d_in[4];
  const int*   rows   = (const int*)d_in[5];
  const int*   cols   = (const int*)d_in[6];
  const float* vals   = (const float*)d_in[7];
  float* out = (float*)d_out;

  const int N   = in_sizes[0] / FEAT;  // 100000
  const int nnz = in_sizes[5];         // 1600000

  // ws layout: cnt [N] i32 | rowsum [N] f32 | entries [N*CAP] int4
  //            | nb [N*64] bf16 | aggb [N*64] bf16  (slot[] overlays aggb:
  //            slot is dead before gather writes aggb)
  int*            cnt     = (int*)d_ws;
  float*          rowsum  = (float*)(cnt + N);
  int4*           entries = (int4*)(rowsum + N);           // 16B-aligned
  unsigned short* nb      = (unsigned short*)(entries + (size_t)N * CAP);
  unsigned short* aggb    = nb + (size_t)N * FEAT;
  int*            slot    = (int*)aggb;   // overlay; needs nnz*4 <= N*FEAT*2 ok
  const size_t need = (size_t)N * 8 + (size_t)N * CAP * 16 + (size_t)N * FEAT * 4;

  if (ws_size >= need && (size_t)nnz * 4 <= (size_t)N * FEAT * 2) {
    hipMemsetAsync(cnt, 0, (size_t)N * sizeof(int), stream);
    const int n8 = N * FEAT / 8;
    const int slot_blocks = (nnz + 255) / 256;   // 6250
    convert_and_slot_kernel<<<CONV_BLOCKS + slot_blocks, 256, 0, stream>>>(
        nodes, nb, n8, rows, cnt, slot, nnz);
    scatter_entries_kernel<<<(nnz + 255) / 256, 256, 0, stream>>>(
        rows, cols, vals, X1, slot, entries, nnz);
    gather_agg_kernel<<<(N + 3) / 4, 256, 0, stream>>>(
        nb, cnt, entries, aggb, rowsum, N);
    final_gemm_kernel<<<1563, 256, 0, stream>>>(aggb, rowsum, W, bias, preluw,
                                                out, N);
  } else {
    float* agg2    = (float*)d_ws;
    float* rowsum2 = agg2 + (size_t)N * FEAT;
    hipMemsetAsync(d_ws, 0, ((size_t)N * FEAT + N) * sizeof(float), stream);
    scatter_xe_kernel<<<4096, 256, 0, stream>>>(nodes, X1, rows, cols, vals,
                                                agg2, rowsum2, nnz);
    final_gemm_f32_kernel<<<1563, 256, 0, stream>>>(agg2, rowsum2, W, bias,
                                                    preluw, out, N);
  }
}

// Round 8
// 202.674 us; speedup vs baseline: 1.1767x; 1.1767x over previous
//
#include <hip/hip_runtime.h>
#include <hip/hip_bf16.h>

// N_NODES=100000, N_EDGES=800000, FEAT=64, NNZ=1600000
// Inputs: 0 edge_list [N,64] f32 | 1 X1 [E,2] i32 | 2 W [64,64] f32 | 3 b [64] f32
//         4 prelu_w [1] f32 | 5 b1_rows [NNZ] i32 | 6 b1_cols [NNZ] i32 | 7 b1_vals [NNZ] f32
// Output: [N,64] f32
//
// out = PReLU( (B1 @ Xe) @ W^T + (B1 @ 1) b^T ),  Xe[c] = (n[u_c]-n[v_c])^2
//
// Round-8: contention fix for the slot histogram. Round-7 isolated the fill
// bottleneck as the 1.6M atomicAdd-with-return on a 400 KB cnt array
// (16 counters/64B line -> ~256 serialized cross-XCD RMWs per line,
// 16.7k atomics/us vs 237k/us when spread). Fix: pad each counter to its
// own 64 B cache line (stride-16 ints). Fill reverts to the fused one-pass
// form. CAP 64->48 keeps ws need (109.2 MB) under the proven budget.

#define FEAT 64
#define CAP  48        // max row degree ~35-40 (Binomial(1.6M,1e-5)); guarded
#define CNT_STRIDE 16  // 64 B per counter: one cache line each

typedef __attribute__((ext_vector_type(8))) short bf16x8;
typedef __attribute__((ext_vector_type(8))) unsigned short u16x8;
typedef __attribute__((ext_vector_type(4))) float f32x4;

__device__ inline short f2bf(float x) {
  union { __hip_bfloat16 h; short s; } u;
  u.h = __float2bfloat16(x);   // RNE
  return u.s;
}
__device__ inline float bf2f(unsigned short s) {
  return __uint_as_float((unsigned)s << 16);
}

// ---------------------------------------------------------------------------
// Kernel 0: f32 -> bf16 node table (one pass, 25.6 MB read / 12.8 MB write).
// ---------------------------------------------------------------------------
__global__ __launch_bounds__(256) void convert_nodes_kernel(
    const float* __restrict__ nodes,      // [N*64]
    unsigned short* __restrict__ nb,      // [N*64]
    int n8) {                             // (N*64)/8
  const int i = blockIdx.x * blockDim.x + threadIdx.x;
  if (i >= n8) return;
  const f32x4 a = *reinterpret_cast<const f32x4*>(&nodes[i * 8]);
  const f32x4 b = *reinterpret_cast<const f32x4*>(&nodes[i * 8 + 4]);
  u16x8 o;
#pragma unroll
  for (int e = 0; e < 4; ++e) {
    o[e]     = (unsigned short)f2bf(a[e]);
    o[4 + e] = (unsigned short)f2bf(b[e]);
  }
  *reinterpret_cast<u16x8*>(&nb[i * 8]) = o;
}

// ---------------------------------------------------------------------------
// Kernel 1: fused fill — one nnz per thread.
//   k = atomicAdd(&cnt[r*CNT_STRIDE], 1)   (padded: no line contention)
//   entries[r*CAP+k] = {u, w, val}         (X1 resolved here, once)
// The atomic and the X1 gather are independent -> both in flight together.
// ---------------------------------------------------------------------------
__global__ __launch_bounds__(256) void fill_entries_kernel(
    const int*   __restrict__ rows,     // [NNZ]
    const int*   __restrict__ cols,     // [NNZ]
    const float* __restrict__ vals,     // [NNZ]
    const int*   __restrict__ X1,       // [E,2]
    int*         __restrict__ cnt,      // [N*CNT_STRIDE] pre-zeroed
    int4*        __restrict__ entries,  // [N*CAP]
    int nnz) {
  const int i = blockIdx.x * blockDim.x + threadIdx.x;
  if (i >= nnz) return;
  const int r = rows[i];
  const int2 uv = reinterpret_cast<const int2*>(X1)[cols[i]];
  const float v = vals[i];
  const int k = atomicAdd(&cnt[(size_t)r * CNT_STRIDE], 1);
  if (k < CAP) {
    entries[(size_t)r * CAP + k] = make_int4(uv.x, uv.y, __float_as_int(v), 0);
  }
}

// ---------------------------------------------------------------------------
// Kernel 2: per-row gather-aggregate from the bf16 node table, 4x unrolled.
// One wave per row; lane j = feature j. agg stored as bf16.
// ---------------------------------------------------------------------------
__global__ __launch_bounds__(256) void gather_agg_kernel(
    const unsigned short* __restrict__ nb,   // [N,64] bf16
    const int*   __restrict__ cnt,           // [N*CNT_STRIDE]
    const int4*  __restrict__ entries,       // [N*CAP]
    unsigned short* __restrict__ aggb,       // [N,64] bf16
    float*       __restrict__ rowsum,        // [N]
    int N) {
  const int lane = threadIdx.x & 63;
  const int r = blockIdx.x * (blockDim.x >> 6) + (threadIdx.x >> 6);
  if (r >= N) return;

  int deg = cnt[(size_t)r * CNT_STRIDE];
  if (deg > CAP) deg = CAP;
  const int4* base = &entries[(size_t)r * CAP];

  float acc = 0.f, rsum = 0.f;

  for (int k = 0; k < deg; k += 4) {
    // 4 wave-uniform entry loads (groups 4-aligned; k+3 <= 47 < CAP).
    const int4 e0 = base[k + 0];
    const int4 e1 = base[k + 1];
    const int4 e2 = base[k + 2];
    const int4 e3 = base[k + 3];

    // Mask the (at most one) partial tail group: index -> 0, weight -> 0.
    const bool m1 = (k + 1 < deg), m2 = (k + 2 < deg), m3 = (k + 3 < deg);
    const int   u0 = e0.x,            w0 = e0.y;
    const int   u1 = m1 ? e1.x : 0,   w1 = m1 ? e1.y : 0;
    const int   u2 = m2 ? e2.x : 0,   w2 = m2 ? e2.y : 0;
    const int   u3 = m3 ? e3.x : 0,   w3 = m3 ? e3.y : 0;
    const float v0 = __int_as_float(e0.z);
    const float v1 = m1 ? __int_as_float(e1.z) : 0.f;
    const float v2 = m2 ? __int_as_float(e2.z) : 0.f;
    const float v3 = m3 ? __int_as_float(e3.z) : 0.f;

    // 8 independent node-row gathers (128B coalesced each, bf16).
    const unsigned short a0 = nb[(size_t)u0 * FEAT + lane];
    const unsigned short b0 = nb[(size_t)w0 * FEAT + lane];
    const unsigned short a1 = nb[(size_t)u1 * FEAT + lane];
    const unsigned short b1 = nb[(size_t)w1 * FEAT + lane];
    const unsigned short a2 = nb[(size_t)u2 * FEAT + lane];
    const unsigned short b2 = nb[(size_t)w2 * FEAT + lane];
    const unsigned short a3 = nb[(size_t)u3 * FEAT + lane];
    const unsigned short b3 = nb[(size_t)w3 * FEAT + lane];

    rsum += (v0 + v1) + (v2 + v3);
    const float d0 = bf2f(a0) - bf2f(b0);
    const float d1 = bf2f(a1) - bf2f(b1);
    const float d2 = bf2f(a2) - bf2f(b2);
    const float d3 = bf2f(a3) - bf2f(b3);
    acc = fmaf(v0 * d0, d0, acc);
    acc = fmaf(v1 * d1, d1, acc);
    acc = fmaf(v2 * d2, d2, acc);
    acc = fmaf(v3 * d3, d3, acc);
  }

  aggb[(size_t)r * FEAT + lane] = (unsigned short)f2bf(acc);
  if (lane == 0) rowsum[r] = rsum;
}

// ---------------------------------------------------------------------------
// Kernel 3: out = PReLU( agg @ W^T + rowsum * b )  via mfma_f32_16x16x32_bf16.
// Fragment layouts (gfx950, m89/m91-verified):
//   A[i][k]: i = lane&15, k = (lane>>4)*8 + e   (e = 0..7)
//   B[k][j]: j = lane&15, k = (lane>>4)*8 + e
//   D[i][j]: j = lane&15, i = (lane>>4)*4 + reg (reg = 0..3)
// ---------------------------------------------------------------------------
__global__ __launch_bounds__(256) void final_gemm_kernel(
    const unsigned short* __restrict__ aggb,  // [N,64] bf16
    const float* __restrict__ rowsum,         // [N]
    const float* __restrict__ W,              // [64,64]
    const float* __restrict__ bias,           // [64]
    const float* __restrict__ pw,             // [1]
    float*       __restrict__ out,            // [N,64]
    int nrows) {
  const int lane = threadIdx.x & 63;
  const int gw = blockIdx.x * (blockDim.x >> 6) + (threadIdx.x >> 6);
  const int nw = gridDim.x * (blockDim.x >> 6);

  const int lrow = lane & 15;
  const int kgrp = lane >> 4;
  const int k0   = kgrp * 8;

  bf16x8 bfrag[4][2];
#pragma unroll
  for (int jt = 0; jt < 4; ++jt) {
#pragma unroll
    for (int ks = 0; ks < 2; ++ks) {
      const float* wr = &W[(jt * 16 + lrow) * FEAT + ks * 32 + k0];
      bf16x8 t;
#pragma unroll
      for (int e = 0; e < 8; ++e) t[e] = f2bf(wr[e]);
      bfrag[jt][ks] = t;
    }
  }
  const float slope = pw[0];
  float bj[4];
#pragma unroll
  for (int jt = 0; jt < 4; ++jt) bj[jt] = bias[jt * 16 + lrow];

  const int ntiles = nrows >> 4;   // 100000 / 16 = 6250
  for (int t = gw; t < ntiles; t += nw) {
    const int rowbase = t * 16;

    bf16x8 afrag[2];
#pragma unroll
    for (int ks = 0; ks < 2; ++ks) {
      afrag[ks] = *reinterpret_cast<const bf16x8*>(
          &aggb[(size_t)(rowbase + lrow) * FEAT + ks * 32 + k0]);
    }

    float rs[4];
#pragma unroll
    for (int reg = 0; reg < 4; ++reg) rs[reg] = rowsum[rowbase + kgrp * 4 + reg];

#pragma unroll
    for (int jt = 0; jt < 4; ++jt) {
      f32x4 acc = {0.f, 0.f, 0.f, 0.f};
      acc = __builtin_amdgcn_mfma_f32_16x16x32_bf16(afrag[0], bfrag[jt][0], acc, 0, 0, 0);
      acc = __builtin_amdgcn_mfma_f32_16x16x32_bf16(afrag[1], bfrag[jt][1], acc, 0, 0, 0);
#pragma unroll
      for (int reg = 0; reg < 4; ++reg) {
        float y = acc[reg] + rs[reg] * bj[jt];
        y = y >= 0.f ? y : slope * y;
        out[(size_t)(rowbase + kgrp * 4 + reg) * FEAT + jt * 16 + lrow] = y;
      }
    }
  }
}

// ---------------------------------------------------------------------------
// Fallback (ws too small): atomic scatter path + f32 GEMM (round-2).
// ---------------------------------------------------------------------------
__global__ __launch_bounds__(256) void scatter_xe_kernel(
    const float* __restrict__ nodes,
    const int*   __restrict__ X1,
    const int*   __restrict__ rows,
    const int*   __restrict__ cols,
    const float* __restrict__ vals,
    float*       __restrict__ agg,
    float*       __restrict__ rowsum,
    int nnz) {
  const int lane = threadIdx.x & 63;
  const int gw = blockIdx.x * (blockDim.x >> 6) + (threadIdx.x >> 6);
  const int nw = gridDim.x * (blockDim.x >> 6);
  for (int i = gw; i < nnz; i += nw) {
    const int r = rows[i];
    const int c = cols[i];
    const float v = vals[i];
    const int u = X1[2 * c + 0];
    const int w = X1[2 * c + 1];
    const float a = nodes[(size_t)u * FEAT + lane];
    const float b = nodes[(size_t)w * FEAT + lane];
    const float d = a - b;
    atomicAdd(&agg[(size_t)r * FEAT + lane], v * d * d);
    if (lane == 0) atomicAdd(&rowsum[r], v);
  }
}

__global__ __launch_bounds__(256) void final_gemm_f32_kernel(
    const float* __restrict__ agg, const float* __restrict__ rowsum,
    const float* __restrict__ W, const float* __restrict__ bias,
    const float* __restrict__ pw, float* __restrict__ out, int nrows) {
  const int lane = threadIdx.x & 63;
  const int gw = blockIdx.x * (blockDim.x >> 6) + (threadIdx.x >> 6);
  const int nw = gridDim.x * (blockDim.x >> 6);
  const int lrow = lane & 15;
  const int kgrp = lane >> 4;
  const int k0   = kgrp * 8;

  bf16x8 bfrag[4][2];
#pragma unroll
  for (int jt = 0; jt < 4; ++jt)
#pragma unroll
    for (int ks = 0; ks < 2; ++ks) {
      const float* wr = &W[(jt * 16 + lrow) * FEAT + ks * 32 + k0];
      bf16x8 t;
#pragma unroll
      for (int e = 0; e < 8; ++e) t[e] = f2bf(wr[e]);
      bfrag[jt][ks] = t;
    }
  const float slope = pw[0];
  float bj[4];
#pragma unroll
  for (int jt = 0; jt < 4; ++jt) bj[jt] = bias[jt * 16 + lrow];

  const int ntiles = nrows >> 4;
  for (int t = gw; t < ntiles; t += nw) {
    const int rowbase = t * 16;
    bf16x8 afrag[2];
#pragma unroll
    for (int ks = 0; ks < 2; ++ks) {
      const float* ar = &agg[(size_t)(rowbase + lrow) * FEAT + ks * 32 + k0];
      f32x4 a0 = *reinterpret_cast<const f32x4*>(ar);
      f32x4 a1 = *reinterpret_cast<const f32x4*>(ar + 4);
      bf16x8 ta;
#pragma unroll
      for (int e = 0; e < 4; ++e) { ta[e] = f2bf(a0[e]); ta[4 + e] = f2bf(a1[e]); }
      afrag[ks] = ta;
    }
    float rs[4];
#pragma unroll
    for (int reg = 0; reg < 4; ++reg) rs[reg] = rowsum[rowbase + kgrp * 4 + reg];
#pragma unroll
    for (int jt = 0; jt < 4; ++jt) {
      f32x4 acc = {0.f, 0.f, 0.f, 0.f};
      acc = __builtin_amdgcn_mfma_f32_16x16x32_bf16(afrag[0], bfrag[jt][0], acc, 0, 0, 0);
      acc = __builtin_amdgcn_mfma_f32_16x16x32_bf16(afrag[1], bfrag[jt][1], acc, 0, 0, 0);
#pragma unroll
      for (int reg = 0; reg < 4; ++reg) {
        float y = acc[reg] + rs[reg] * bj[jt];
        y = y >= 0.f ? y : slope * y;
        out[(size_t)(rowbase + kgrp * 4 + reg) * FEAT + jt * 16 + lrow] = y;
      }
    }
  }
}

extern "C" void kernel_launch(void* const* d_in, const int* in_sizes, int n_in,
                              void* d_out, int out_size, void* d_ws, size_t ws_size,
                              hipStream_t stream) {
  const float* nodes  = (const float*)d_in[0];
  const int*   X1     = (const int*)d_in[1];
  const float* W      = (const float*)d_in[2];
  const float* bias   = (const float*)d_in[3];
  const float* preluw = (const float*)d_in[4];
  const int*   rows   = (const int*)d_in[5];
  const int*   cols   = (const int*)d_in[6];
  const float* vals   = (const float*)d_in[7];
  float* out = (float*)d_out;

  const int N   = in_sizes[0] / FEAT;  // 100000
  const int nnz = in_sizes[5];         // 1600000

  // ws layout: cnt [N*CNT_STRIDE] i32 (6.4 MB, one 64B line per counter)
  //          | rowsum [N] f32 | entries [N*CAP] int4 (76.8 MB)
  //          | nb [N*64] bf16 (12.8 MB) | aggb [N*64] bf16 (12.8 MB)
  // total need = 109.2 MB  (< proven-available 128.8 MB)
  int*            cnt     = (int*)d_ws;
  float*          rowsum  = (float*)(cnt + (size_t)N * CNT_STRIDE);
  int4*           entries = (int4*)(rowsum + N);  // 6.8 MB offset, 16B-aligned
  unsigned short* nb      = (unsigned short*)(entries + (size_t)N * CAP);
  unsigned short* aggb    = nb + (size_t)N * FEAT;
  const size_t need = (size_t)N * CNT_STRIDE * 4 + (size_t)N * 4 +
                      (size_t)N * CAP * 16 + (size_t)N * FEAT * 4;

  if (ws_size >= need) {
    hipMemsetAsync(cnt, 0, (size_t)N * CNT_STRIDE * sizeof(int), stream);
    const int n8 = N * FEAT / 8;
    convert_nodes_kernel<<<(n8 + 255) / 256, 256, 0, stream>>>(nodes, nb, n8);
    fill_entries_kernel<<<(nnz + 255) / 256, 256, 0, stream>>>(
        rows, cols, vals, X1, cnt, entries, nnz);
    gather_agg_kernel<<<(N + 3) / 4, 256, 0, stream>>>(
        nb, cnt, entries, aggb, rowsum, N);
    final_gemm_kernel<<<1563, 256, 0, stream>>>(aggb, rowsum, W, bias, preluw,
                                                out, N);
  } else {
    float* agg2    = (float*)d_ws;
    float* rowsum2 = agg2 + (size_t)N * FEAT;
    hipMemsetAsync(d_ws, 0, ((size_t)N * FEAT + N) * sizeof(float), stream);
    scatter_xe_kernel<<<4096, 256, 0, stream>>>(nodes, X1, rows, cols, vals,
                                                agg2, rowsum2, nnz);
    final_gemm_f32_kernel<<<1563, 256, 0, stream>>>(agg2, rowsum2, W, bias,
                                                    preluw, out, N);
  }
}